// Round 11
// baseline (73.286 us; speedup 1.0000x reference)
//
#include <hip/hip_runtime.h>

#define ND 1024
#define NNE (ND*ND)

typedef __bf16 bf16x8 __attribute__((ext_vector_type(8)));
typedef float f32x4 __attribute__((ext_vector_type(4)));
typedef int i32x4 __attribute__((ext_vector_type(4)));
typedef int i32x8 __attribute__((ext_vector_type(8)));

__device__ __forceinline__ unsigned short f2bf(float f) {
  unsigned u = __float_as_uint(f);
  u += 0x7fffu + ((u >> 16) & 1u);
  return (unsigned short)(u >> 16);
}

__device__ __forceinline__ void gload_lds16(const void* g, void* l) {
  __builtin_amdgcn_global_load_lds(
      (const __attribute__((address_space(1))) void*)g,
      (__attribute__((address_space(3))) void*)l, 16, 0, 0);
}

// ---- fused: zero phi row, convert x row -> bf16, phi[b,f,0] = x . lowpass ----
__global__ void convert_phi0_kernel(const float* __restrict__ x, const float* __restrict__ lp,
                                    unsigned short* __restrict__ xb, float* __restrict__ phi) {
  __shared__ float ws[4];
  int row = blockIdx.x;
  int t   = threadIdx.x;
  if (t >= 1 && t < 73) phi[row * 73 + t] = 0.f;   // replaces hipMemsetAsync
  float4 v = reinterpret_cast<const float4*>(x + (size_t)row * ND)[t];
  float4 l = reinterpret_cast<const float4*>(lp)[t];
  ushort4 o;
  o.x = f2bf(v.x); o.y = f2bf(v.y); o.z = f2bf(v.z); o.w = f2bf(v.w);
  reinterpret_cast<ushort4*>(xb + (size_t)row * ND)[t] = o;
  float s = v.x * l.x + v.y * l.y + v.z * l.z + v.w * l.w;
  #pragma unroll
  for (int off = 32; off; off >>= 1) s += __shfl_xor(s, off);
  if ((t & 63) == 0) ws[t >> 6] = s;
  __syncthreads();
  if (t == 0) phi[row * 73] = ws[0] + ws[1] + ws[2] + ws[3];
}

// ---- transpose+convert psi: bf16 out[j][m][n] AND fp8 out8[j][m][n] = psi[j][n][m] ----
__global__ void psi_transpose_kernel(const float* __restrict__ psi,
                                     unsigned short* __restrict__ out,
                                     unsigned char* __restrict__ out8) {
  __shared__ float t[32][33];
  int blk = blockIdx.x;
  int j  = blk >> 10;
  int tn = (blk >> 5) & 31;
  int tm = blk & 31;
  const float* src = psi + ((size_t)j << 20) + (size_t)(tn << 5) * ND + (tm << 5);
  int r  = threadIdx.x >> 3;
  int c4 = (threadIdx.x & 7) << 2;
  float4 v = *reinterpret_cast<const float4*>(src + (size_t)r * ND + c4);
  t[r][c4 + 0] = v.x; t[r][c4 + 1] = v.y; t[r][c4 + 2] = v.z; t[r][c4 + 3] = v.w;
  __syncthreads();
  float f0 = t[c4 + 0][r], f1 = t[c4 + 1][r], f2 = t[c4 + 2][r], f3 = t[c4 + 3][r];
  ushort4 o;
  o.x = f2bf(f0); o.y = f2bf(f1); o.z = f2bf(f2); o.w = f2bf(f3);
  size_t base = ((size_t)j << 20) + (size_t)((tm << 5) + r) * ND + (tn << 5) + c4;
  *reinterpret_cast<ushort4*>(out + base) = o;
  int pk = __builtin_amdgcn_cvt_pk_fp8_f32(f0, f1, 0, false);
  pk = __builtin_amdgcn_cvt_pk_fp8_f32(f2, f3, pk, true);
  *reinterpret_cast<unsigned int*>(out8 + base) = (unsigned int)pk;
}

// ==== layer-1 GEMM (verified round-0 structure; stores S1 as fp8) ====
template<int BM, int BN>
__global__ __launch_bounds__(256)
void gemm_scat(const unsigned short* __restrict__ A,
               const unsigned short* __restrict__ BT,
               const float* __restrict__ lowpass,
               unsigned char* __restrict__ Sout,
               float* __restrict__ phi) {
  constexpr int BK = 64;
  constexpr int WM = BM / 2, WN = BN / 2;
  constexpr int MF = WM / 16, NF = WN / 16;

  __shared__ __align__(16) unsigned short Asm[BM * BK];
  __shared__ __align__(16) unsigned short Bsm[BN * BK];

  const int tid  = threadIdx.x;
  const int lane = tid & 63;
  const int w    = tid >> 6;
  const int wrow = w >> 1, wcol = w & 1;

  const int j    = blockIdx.z;
  const int row0 = blockIdx.y * BM;
  const int n0   = blockIdx.x * BN;

  const unsigned short* Bj = BT + (size_t)j * NNE;

  f32x4 acc[MF][NF] = {};

  constexpr int ACH = BM * 8;
  constexpr int BCH = BN * 8;

  for (int k0 = 0; k0 < ND; k0 += BK) {
    __syncthreads();
    #pragma unroll
    for (int p = 0; p < ACH / 256; ++p) {
      int c = p * 256 + tid;
      int r = c >> 3;
      int s = (c & 7) ^ (r & 7);
      gload_lds16(A + (size_t)(row0 + r) * ND + k0 + s * 8, Asm + c * 8);
    }
    #pragma unroll
    for (int p = 0; p < BCH / 256; ++p) {
      int c = p * 256 + tid;
      int r = c >> 3;
      int s = (c & 7) ^ (r & 7);
      gload_lds16(Bj + (size_t)(n0 + r) * ND + k0 + s * 8, Bsm + c * 8);
    }
    __syncthreads();

    #pragma unroll
    for (int kk = 0; kk < 2; ++kk) {
      bf16x8 a[MF], b[NF];
      int srd = kk * 4 + (lane >> 4);
      #pragma unroll
      for (int m = 0; m < MF; ++m) {
        int r = wrow * WM + m * 16 + (lane & 15);
        a[m] = *reinterpret_cast<const bf16x8*>(&Asm[r * 64 + ((srd ^ (r & 7)) * 8)]);
      }
      #pragma unroll
      for (int n = 0; n < NF; ++n) {
        int r = wcol * WN + n * 16 + (lane & 15);
        b[n] = *reinterpret_cast<const bf16x8*>(&Bsm[r * 64 + ((srd ^ (r & 7)) * 8)]);
      }
      #pragma unroll
      for (int m = 0; m < MF; ++m)
        #pragma unroll
        for (int n = 0; n < NF; ++n)
          acc[m][n] = __builtin_amdgcn_mfma_f32_16x16x32_bf16(a[m], b[n], acc[m][n], 0, 0, 0);
    }
  }

  float lp[NF];
  #pragma unroll
  for (int n = 0; n < NF; ++n)
    lp[n] = lowpass[n0 + wcol * WN + n * 16 + (lane & 15)];

  #pragma unroll
  for (int m = 0; m < MF; ++m) {
    #pragma unroll
    for (int r = 0; r < 4; ++r) {
      int rg = row0 + wrow * WM + m * 16 + (lane >> 4) * 4 + r;
      float psum = 0.f;
      #pragma unroll
      for (int n = 0; n < NF; ++n) {
        float v = fabsf(acc[m][n][r]);
        psum += v * lp[n];
        int colg = n0 + wcol * WN + n * 16 + (lane & 15);
        size_t si = ((size_t)((rg >> 4) * 8 + j) * 16 + (rg & 15)) * ND + colg;
        int pk = __builtin_amdgcn_cvt_pk_fp8_f32(v, v, 0, false);
        Sout[si] = (unsigned char)(pk & 0xff);
      }
      psum += __shfl_xor(psum, 1);
      psum += __shfl_xor(psum, 2);
      psum += __shfl_xor(psum, 4);
      psum += __shfl_xor(psum, 8);
      if ((lane & 15) == 0) {
        int pidx = rg * 73 + 1 + j;
        atomicAdd(&phi[pidx], psum);
      }
    }
  }
}

// ==== layer-2: MX-fp8 (scale=1) 256x256 tile, 8 waves (128x64), BK=128,
//      4-phase rhythm + 2-ahead staging + counted vmcnt(8) gate (T4) ====

// one 32B fp8 fragment: two swizzled ds_read_b128 combined (k-order preserved)
__device__ __forceinline__ i32x8 dsr_frag8(const unsigned char* base, int r, int l4) {
  int s0 = l4 * 2;
  i32x4 lo = *reinterpret_cast<const i32x4*>(base + r * 128 + ((s0 ^ (r & 7)) << 4));
  i32x4 hi = *reinterpret_cast<const i32x4*>(base + r * 128 + (((s0 + 1) ^ (r & 7)) << 4));
  return __builtin_shufflevector(lo, hi, 0, 1, 2, 3, 4, 5, 6, 7);
}

template<int MH>
__device__ __forceinline__ void dsr_a8(i32x8 (&dst)[4], const unsigned char* base,
                                       int wrow, int l15, int l4) {
  #pragma unroll
  for (int m = 0; m < 4; ++m)
    dst[m] = dsr_frag8(base, wrow * 128 + (MH + m) * 16 + l15, l4);
}

template<int NL>
__device__ __forceinline__ void dsr_b8(i32x8 (&dst)[2], const unsigned char* base,
                                       int wcol, int l15, int l4) {
  #pragma unroll
  for (int n = 0; n < 2; ++n)
    dst[n] = dsr_frag8(base, wcol * 64 + (NL + n) * 16 + l15, l4);
}

template<int MH, int NL>
__device__ __forceinline__ void mfma_q8(f32x4 (&acc)[8][4], const i32x8 (&a)[4],
                                        const i32x8 (&b)[2]) {
  #pragma unroll
  for (int m = 0; m < 4; ++m)
    #pragma unroll
    for (int n = 0; n < 2; ++n)
      acc[MH + m][NL + n] = __builtin_amdgcn_mfma_scale_f32_16x16x128_f8f6f4(
          a[m], b[n], acc[MH + m][NL + n], 0, 0, 0, 0x7f7f7f7f, 0, 0x7f7f7f7f);
}

// stage one 256x128B fp8 K-tile (2048 chunks, 4 per thread at 512 thr)
__device__ __forceinline__ void stage_tile8(const unsigned char* __restrict__ g, int grow0,
                                            int kofs, unsigned char* l, int tid) {
  #pragma unroll
  for (int p = 0; p < 4; ++p) {
    int c = p * 512 + tid;
    int r = c >> 3;
    int s = (c & 7) ^ (r & 7);
    gload_lds16(g + (size_t)(grow0 + r) * ND + kofs + (s << 4), l + (size_t)c * 16);
  }
}

#define SBAR()  __builtin_amdgcn_s_barrier()
#define SCHED0() __builtin_amdgcn_sched_barrier(0)
#define WAIT_LGKM0() do { asm volatile("s_waitcnt lgkmcnt(0)" ::: "memory"); SCHED0(); } while (0)
#define WAIT_VM(N) do { asm volatile("s_waitcnt vmcnt(" #N ")" ::: "memory"); SCHED0(); } while (0)
#define PRIO_MFMA(stmt) do { __builtin_amdgcn_s_setprio(1); stmt; __builtin_amdgcn_s_setprio(0); SCHED0(); } while (0)

__global__ __launch_bounds__(512, 2)
void gemm_scat2(const unsigned char* __restrict__ A,
                const unsigned char* __restrict__ BT,
                const float* __restrict__ lowpass,
                float* __restrict__ phi) {
  extern __shared__ __align__(16) unsigned char smem[];
  unsigned char* As0 = smem;                 // [256][128] fp8, 32 KB each
  unsigned char* As1 = smem + 32768;
  unsigned char* Bs0 = smem + 65536;
  unsigned char* Bs1 = smem + 98304;

  const int tid  = threadIdx.x;
  const int lane = tid & 63;
  const int w    = tid >> 6;          // 8 waves: 2M x 4N
  const int wrow = w >> 2, wcol = w & 3;
  const int l15  = lane & 15, l4 = lane >> 4;

  int wg = blockIdx.x;
  const int j = wg & 7;               // j per XCD
  const int t = wg >> 3;              // 0..31
  const int mtile = t & 7, ntile = t >> 3;
  const int row0 = mtile * 256, n0 = ntile * 256;
  const unsigned char* Bj = BT + (size_t)j * NNE;

  f32x4 acc[8][4] = {};
  i32x8 aX[4], bL[2], bH[2];

  // prologue: stage K-tiles 0 and 1; gate tile0 only (tile1 stays in flight)
  stage_tile8(A,  row0, 0,   As0, tid);
  stage_tile8(Bj, n0,   0,   Bs0, tid);
  stage_tile8(A,  row0, 128, As1, tid);
  stage_tile8(Bj, n0,   128, Bs1, tid);
  WAIT_VM(8);
  SBAR();

  #pragma unroll 1
  for (int i = 0; i < 8; ++i) {
    unsigned char* Ac = (i & 1) ? As1 : As0;
    unsigned char* Bc = (i & 1) ? Bs1 : Bs0;
    const int knext2 = (i + 2) * 128;

    // P0: dsr aLo + bLo; MFMA Q(0,0)
    dsr_a8<0>(aX, Ac, wrow, l15, l4);
    dsr_b8<0>(bL, Bc, wcol, l15, l4);
    SBAR(); WAIT_LGKM0();
    PRIO_MFMA((mfma_q8<0,0>(acc, aX, bL)));
    SBAR();
    // P1: dsr bHi; MFMA Q(0,2)
    dsr_b8<2>(bH, Bc, wcol, l15, l4);
    SBAR(); WAIT_LGKM0();
    PRIO_MFMA((mfma_q8<0,2>(acc, aX, bH)));
    SBAR();
    // P2: dsr aHi (overwrite aX); MFMA Q(4,0); trailing SBAR certifies all
    //     waves done reading tile i's buffers (their last reads drained here)
    dsr_a8<4>(aX, Ac, wrow, l15, l4);
    SBAR(); WAIT_LGKM0();
    PRIO_MFMA((mfma_q8<4,0>(acc, aX, bL)));
    SBAR();
    // P3: stage tile i+2 into the just-freed cur buffers; MFMA Q(4,2);
    //     counted gate: tile i+2's 8 loads stay in flight, tile i+1 certified
    if (i < 6) {
      stage_tile8(A,  row0, knext2, Ac, tid);
      stage_tile8(Bj, n0,   knext2, Bc, tid);
    }
    SCHED0();
    PRIO_MFMA((mfma_q8<4,2>(acc, aX, bH)));
    if (i < 6)       { WAIT_VM(8); }
    else if (i == 6) { WAIT_VM(0); }
    SBAR();
  }

  // epilogue: abs + lowpass dot + atomics into phi[...,9+k*8+j]
  float lp[4];
  #pragma unroll
  for (int n = 0; n < 4; ++n)
    lp[n] = lowpass[n0 + wcol * 64 + n * 16 + l15];

  #pragma unroll
  for (int m = 0; m < 8; ++m) {
    #pragma unroll
    for (int r = 0; r < 4; ++r) {
      int rg = row0 + wrow * 128 + m * 16 + l4 * 4 + r;
      float psum = 0.f;
      #pragma unroll
      for (int n = 0; n < 4; ++n)
        psum += fabsf(acc[m][n][r]) * lp[n];
      psum += __shfl_xor(psum, 1);
      psum += __shfl_xor(psum, 2);
      psum += __shfl_xor(psum, 4);
      psum += __shfl_xor(psum, 8);
      if (l15 == 0) {
        int pidx = ((rg >> 7) * 16 + (rg & 15)) * 73 + 9 + ((rg >> 4) & 7) * 8 + j;
        atomicAdd(&phi[pidx], psum);
      }
    }
  }
}

extern "C" void kernel_launch(void* const* d_in, const int* in_sizes, int n_in,
                              void* d_out, int out_size, void* d_ws, size_t ws_size,
                              hipStream_t stream) {
  (void)in_sizes; (void)n_in; (void)ws_size; (void)out_size;
  const float* x       = (const float*)d_in[0];
  const float* psi     = (const float*)d_in[1];
  const float* lowpass = (const float*)d_in[2];
  float* phi = (float*)d_out;

  unsigned short* xb    = (unsigned short*)d_ws;                        // 512 KB
  unsigned short* psiT  = (unsigned short*)((char*)d_ws + (1u  << 20)); // 16 MB  (bf16, layer-1)
  unsigned char*  S1f8  = (unsigned char*) ((char*)d_ws + (17u << 20)); // 2 MB   (fp8, layer-2 A)
  unsigned char*  psiT8 = (unsigned char*) ((char*)d_ws + (19u << 20)); // 8 MB   (fp8, layer-2 B)

  convert_phi0_kernel<<<256, 256, 0, stream>>>(x, lowpass, xb, phi);
  psi_transpose_kernel<<<8192, 256, 0, stream>>>(psi, psiT, psiT8);

  // layer 1: bf16 MFMA, M=256, tiles 64x128 -> grid (8, 4, 8); stores S1 as fp8
  gemm_scat<64, 128><<<dim3(8, 4, 8), 256, 0, stream>>>(xb, psiT, lowpass, S1f8, phi);

  // layer 2: MX-fp8 (scale=1) 16x16x128 MFMA, 256x256 tiles, 128 KiB LDS, 256 blocks
  static int attr_set = 0;
  if (!attr_set) {
    hipFuncSetAttribute((const void*)gemm_scat2,
                        hipFuncAttributeMaxDynamicSharedMemorySize, 131072);
    attr_set = 1;
  }
  gemm_scat2<<<256, 512, 131072, stream>>>(S1f8, psiT8, lowpass, phi);
}